// Round 1
// baseline (347.964 us; speedup 1.0000x reference)
//
#include <hip/hip_runtime.h>
#include <hip/hip_bf16.h>

// SynthesisBlock: modulated 3x3 conv (StyleGAN2-style) on MI355X.
// B=16, Cin=Cout=512, H=W=64, L=512, K=3.
//
// Decomposition:
//   style[b][ci] = latent[b]·affine_w[ci]·sqrt(1/512) + affine_b[ci]
//   xs[b][y][x][ci] = bf16(content[b][ci][y][x] * style[b][ci])   (channel-last)
//   wt[tap][co][ci] = bf16(conv_w[co][ci][tap])
//   dem[b][co] = rsqrt(sum_ci wsq[co][ci]*style[b][ci]^2 + 1e-8)
//   out = lrelu(dem*conv(xs,wt) + nw*noise + bias, 0.2)*sqrt(2)

typedef float f32x4 __attribute__((ext_vector_type(4)));
typedef short bf16x8 __attribute__((ext_vector_type(8)));
typedef int i32x4 __attribute__((ext_vector_type(4)));

#define BB 16
#define CIN 512
#define COUT 512
#define HH 64
#define WW 64
#define LL 512

// ws layout (bytes)
#define XS_OFF 0
#define XS_SZ (BB * HH * WW * CIN * 2)          // 67108864
#define WT_OFF (XS_OFF + XS_SZ)                  // 67108864
#define WT_SZ (9 * COUT * CIN * 2)               // 4718592
#define STYLE_OFF (WT_OFF + WT_SZ)               // 71827456
#define STYLE_SZ (BB * CIN * 4)                  // 32768
#define WSQ_OFF (STYLE_OFF + STYLE_SZ)           // 71860224
#define WSQ_SZ (COUT * CIN * 4)                  // 1048576
#define DEM_OFF (WSQ_OFF + WSQ_SZ)               // 72908800
#define DEM_SZ (BB * COUT * 4)
#define WS_NEEDED (DEM_OFF + DEM_SZ)             // ~72.9 MB

// conv kernel LDS geometry
#define XS_STRIDE 66                              // s = x+dx in [0,65], halo cols
#define XROWB (XS_STRIDE * 64)                    // 4224 B per staged row (64B/pixel = 32ci bf16)
#define XROWS 6                                   // 4 output rows + 2 halo rows
#define XSZ (XROWS * XROWB)                       // 25344
#define WTAPB (64 * 64)                           // 4096 B per tap (64 co x 64B)
#define WSZ (9 * WTAPB)                           // 36864
#define LDSZ (XSZ + WSZ)                          // 62208 < 64KB

__device__ __forceinline__ void gld_lds16(const void* g, void* l) {
  __builtin_amdgcn_global_load_lds(
      (const __attribute__((address_space(1))) unsigned int*)g,
      (__attribute__((address_space(3))) unsigned int*)l, 16, 0, 0);
}

// ---------------- K1: style ----------------
__global__ void style_kernel(const float* __restrict__ latent,
                             const float* __restrict__ affine_w,
                             const float* __restrict__ affine_b,
                             float* __restrict__ style) {
  const int idx = blockIdx.x * 256 + threadIdx.x;   // 8192
  const int b = idx >> 9, ci = idx & 511;
  const float* lp = latent + b * LL;
  const float* wp = affine_w + ci * LL;
  float acc = 0.f;
  for (int l = 0; l < LL; ++l) acc += lp[l] * wp[l];
  style[idx] = acc * 0.044194173824159216f + affine_b[ci];  // sqrt(1/512)
}

// ---------------- K2: weight sumsq + bf16 tap-major transform ----------------
__global__ void wprep_kernel(const float* __restrict__ conv_w,
                             float* __restrict__ wsq,
                             __hip_bfloat16* __restrict__ wt) {
  const int idx = blockIdx.x * 256 + threadIdx.x;   // 262144 = co*512+ci
  const int co = idx >> 9, ci = idx & 511;
  const float* wp = conv_w + idx * 9;
  float ss = 0.f;
#pragma unroll
  for (int t = 0; t < 9; ++t) {
    float v = wp[t];
    ss += v * v;
    wt[(t * COUT + co) * CIN + ci] = __float2bfloat16(v);
  }
  wsq[idx] = ss;
}

// ---------------- K3: demodulation scale ----------------
__global__ void dem_kernel(const float* __restrict__ wsq,
                           const float* __restrict__ style,
                           float* __restrict__ dem) {
  const int idx = blockIdx.x * 256 + threadIdx.x;   // 8192 = b*512+co
  const int b = idx >> 9, co = idx & 511;
  const float* sp = style + b * CIN;
  const float* wp = wsq + co * CIN;
  float acc = 0.f;
  for (int ci = 0; ci < CIN; ++ci) {
    float s = sp[ci];
    acc += wp[ci] * s * s;
  }
  dem[idx] = 1.0f / sqrtf(acc + 1e-8f);
}

// ---------------- K4: modulate + transpose to channel-last bf16 ----------------
__global__ void xsprep_kernel(const float* __restrict__ content,
                              const float* __restrict__ style,
                              __hip_bfloat16* __restrict__ xs) {
  __shared__ float tile[64][65];
  const int b = blockIdx.x >> 6;
  const int y = blockIdx.x & 63;
  const int tid = threadIdx.x;
  for (int cb = 0; cb < 8; ++cb) {
    const int ci0 = cb * 64;
    {
      const int x = tid & 63;
      const int c0 = tid >> 6;
#pragma unroll
      for (int p = 0; p < 16; ++p) {
        const int ci = p * 4 + c0;
        tile[ci][x] = content[((b * CIN + ci0 + ci) * HH + y) * WW + x];
      }
    }
    __syncthreads();
    {
      const int ci = tid & 63;
      const int x0 = tid >> 6;
      const float st = style[b * CIN + ci0 + ci];
#pragma unroll
      for (int p = 0; p < 16; ++p) {
        const int x = p * 4 + x0;
        xs[((b * HH + y) * WW + x) * CIN + ci0 + ci] =
            __float2bfloat16(tile[ci][x] * st);
      }
    }
    __syncthreads();
  }
}

// ---------------- K5: main MFMA conv ----------------
// grid: 16 b x 16 yq x 8 cot = 2048 blocks, 256 threads (4 waves).
// Block tile: 64 co x 256 px (4 rows). Wave w owns output row y0+w, 4x4 frags.
__global__ __launch_bounds__(256, 2) void conv_kernel(
    const __hip_bfloat16* __restrict__ xs,   // [B][H][W][CIN]
    const __hip_bfloat16* __restrict__ wt,   // [9][COUT][CIN]
    const float* __restrict__ dem,           // [B][COUT]
    const float* __restrict__ noise,         // [B][1][H][W]
    const float* __restrict__ biasp,         // [COUT]
    const float* __restrict__ nwp,           // scalar
    float* __restrict__ out) {
  __shared__ __attribute__((aligned(16))) char lds[LDSZ];

  const int tid = threadIdx.x;
  const int lane = tid & 63;
  const int wv = tid >> 6;
  const int bid = blockIdx.x;
  const int cot = bid & 7;
  const int yq = (bid >> 3) & 15;
  const int b = bid >> 7;
  const int co0 = cot << 6;
  const int y0 = yq << 2;

  // zero X region (halo rows/cols stay zero; interior overwritten each step)
  for (int off = tid * 16; off < XSZ; off += 256 * 16)
    *(i32x4*)(lds + off) = (i32x4){0, 0, 0, 0};

  const int l15 = lane & 15;
  const int kg = lane >> 4;

  // per-lane LDS fragment-read offsets (XOR swizzle on 16B ci-chunk slot)
  int aoff[4];
#pragma unroll
  for (int mf = 0; mf < 4; ++mf) {
    const int co_l = l15 + mf * 16;
    const int fs = (co_l & 3) ^ ((co_l >> 2) & 3);
    aoff[mf] = co_l * 64 + ((kg ^ fs) << 4);
  }
  int boff[4][3];
#pragma unroll
  for (int nf = 0; nf < 4; ++nf)
#pragma unroll
    for (int dx = 0; dx < 3; ++dx) {
      const int s = nf * 16 + l15 + dx;
      const int fs = (s & 3) ^ ((s >> 2) & 3);
      boff[nf][dx] = s * 64 + ((kg ^ fs) << 4);
    }

  // staging geometry
  const int rlo = (yq == 0) ? 1 : 0;
  const int rhi = (yq == 15) ? 4 : 5;
  const int nxc = (rhi - rlo + 1) * 4;   // X chunks (1KB each)
  const int ntot = nxc + 36;             // + W chunks: 9 taps x 4

  const int xsub = lane >> 2;   // 0..15 within chunk
  const int slotl = lane & 3;   // 16B slot within 64B pixel/co block

  f32x4 acc[4][4];
#pragma unroll
  for (int mf = 0; mf < 4; ++mf)
#pragma unroll
    for (int nf = 0; nf < 4; ++nf) acc[mf][nf] = (f32x4){0.f, 0.f, 0.f, 0.f};

  __syncthreads();  // zero-init visible before first stage

  for (int cib = 0; cib < 16; ++cib) {
    const int ci0 = cib * 32;
    // ---- stage X interior rows + all 9 W taps ----
    for (int c = wv; c < ntot; c += 4) {
      if (c < nxc) {
        const int r = rlo + (c >> 2);
        const int q = c & 3;
        const int s = 1 + q * 16 + xsub;
        const int x = s - 1;
        const int y = y0 + r - 1;
        const int dcig = slotl ^ ((s & 3) ^ ((s >> 2) & 3));  // pre-swizzled source
        const __hip_bfloat16* g =
            xs + (((b << 6) + y) << 6 | x) * CIN + ci0 + dcig * 8;
        gld_lds16(g, lds + r * XROWB + 64 + q * 1024);
      } else {
        const int cw = c - nxc;
        const int tap = cw >> 2;
        const int q = cw & 3;
        const int co = q * 16 + xsub;
        const int dcig = slotl ^ ((co & 3) ^ ((co >> 2) & 3));
        const __hip_bfloat16* g =
            wt + ((tap << 9) + co0 + co) * CIN + ci0 + dcig * 8;
        gld_lds16(g, lds + XSZ + tap * WTAPB + q * 1024);
      }
    }
    __syncthreads();  // staged data visible (compiler drains vmcnt before barrier)

    // ---- compute: 9 taps x 4x4 frags ----
#pragma unroll
    for (int dy = 0; dy < 3; ++dy) {
      const int rbase = (wv + dy) * XROWB;
#pragma unroll
      for (int dx = 0; dx < 3; ++dx) {
        const int tap = dy * 3 + dx;
        bf16x8 a[4];
#pragma unroll
        for (int mf = 0; mf < 4; ++mf)
          a[mf] = *(const bf16x8*)(lds + XSZ + tap * WTAPB + aoff[mf]);
#pragma unroll
        for (int nf = 0; nf < 4; ++nf) {
          const bf16x8 bfr = *(const bf16x8*)(lds + rbase + boff[nf][dx]);
#pragma unroll
          for (int mf = 0; mf < 4; ++mf)
            acc[mf][nf] = __builtin_amdgcn_mfma_f32_16x16x32_bf16(
                a[mf], bfr, acc[mf][nf], 0, 0, 0);
        }
      }
    }
    __syncthreads();  // compute done before next-step overwrite
  }

  // ---- epilogue: demod scale, noise, bias, lrelu*sqrt(2) ----
  const float nwv = nwp[0];
  const int y = y0 + wv;
  float nz[4];
#pragma unroll
  for (int nf = 0; nf < 4; ++nf)
    nz[nf] = nwv * noise[(b << 12) + (y << 6) + nf * 16 + l15];

#pragma unroll
  for (int mf = 0; mf < 4; ++mf) {
    const int cobase = co0 + mf * 16 + kg * 4;
    const f32x4 dm = *(const f32x4*)(dem + (b << 9) + cobase);
    const f32x4 bs = *(const f32x4*)(biasp + cobase);
#pragma unroll
    for (int r2 = 0; r2 < 4; ++r2) {
      const int co = cobase + r2;
      float* op = out + ((((b << 9) + co) << 12) | (y << 6) | l15);
      const float d = dm[r2];
      const float bsv = bs[r2];
#pragma unroll
      for (int nf = 0; nf < 4; ++nf) {
        float v = acc[mf][nf][r2] * d + nz[nf] + bsv;
        v = (v > 0.f ? v : 0.2f * v) * 1.41421356237309515f;
        op[nf * 16] = v;
      }
    }
  }
}

extern "C" void kernel_launch(void* const* d_in, const int* in_sizes, int n_in,
                              void* d_out, int out_size, void* d_ws, size_t ws_size,
                              hipStream_t stream) {
  const float* content  = (const float*)d_in[0];
  const float* latent   = (const float*)d_in[1];
  const float* noise    = (const float*)d_in[2];
  const float* affine_w = (const float*)d_in[3];
  const float* affine_b = (const float*)d_in[4];
  const float* conv_w   = (const float*)d_in[5];
  const float* bias     = (const float*)d_in[6];
  const float* nw       = (const float*)d_in[7];
  float* out = (float*)d_out;
  char* ws = (char*)d_ws;

  if (ws_size < (size_t)WS_NEEDED) return;  // visible failure, no corruption

  __hip_bfloat16* xs = (__hip_bfloat16*)(ws + XS_OFF);
  __hip_bfloat16* wt = (__hip_bfloat16*)(ws + WT_OFF);
  float* style = (float*)(ws + STYLE_OFF);
  float* wsq   = (float*)(ws + WSQ_OFF);
  float* dem   = (float*)(ws + DEM_OFF);

  style_kernel<<<dim3(32), dim3(256), 0, stream>>>(latent, affine_w, affine_b, style);
  wprep_kernel<<<dim3(1024), dim3(256), 0, stream>>>(conv_w, wsq, wt);
  dem_kernel<<<dim3(32), dim3(256), 0, stream>>>(wsq, style, dem);
  xsprep_kernel<<<dim3(1024), dim3(256), 0, stream>>>(content, style, xs);
  conv_kernel<<<dim3(2048), dim3(256), 0, stream>>>(xs, wt, dem, noise, bias, nw, out);
}

// Round 2
// 313.171 us; speedup vs baseline: 1.1111x; 1.1111x over previous
//
#include <hip/hip_runtime.h>
#include <hip/hip_bf16.h>

// SynthesisBlock: modulated 3x3 conv (StyleGAN2-style) on MI355X.
// R2: wave tile 64co x 2rows x 64px (mf=4, nf=8), input-row fragment reuse
//     across (r,dy), XCD-aware block swizzle. LDS-read traffic 512->299 B/MFMA.

typedef float f32x4 __attribute__((ext_vector_type(4)));
typedef short bf16x8 __attribute__((ext_vector_type(8)));
typedef int i32x4 __attribute__((ext_vector_type(4)));

#define BB 16
#define CIN 512
#define COUT 512
#define HH 64
#define WW 64
#define LL 512

// ws layout (bytes)
#define XS_OFF 0
#define XS_SZ (BB * HH * WW * CIN * 2)          // 67108864
#define WT_OFF (XS_OFF + XS_SZ)                  // 67108864
#define WT_SZ (9 * COUT * CIN * 2)               // 4718592
#define STYLE_OFF (WT_OFF + WT_SZ)               // 71827456
#define STYLE_SZ (BB * CIN * 4)
#define WSQ_OFF (STYLE_OFF + STYLE_SZ)
#define WSQ_SZ (COUT * CIN * 4)
#define DEM_OFF (WSQ_OFF + WSQ_SZ)
#define DEM_SZ (BB * COUT * 4)
#define WS_NEEDED (DEM_OFF + DEM_SZ)             // ~72.9 MB

// conv kernel LDS geometry
#define XS_STRIDE 66                              // s = x+dx in [0,65], halo cols
#define XROWB (XS_STRIDE * 64)                    // 4224 B per staged row (64B/px = 32ci bf16)
#define XROWS 10                                  // 8 output rows + 2 halo rows
#define XSZ (XROWS * XROWB)                       // 42240
#define WTAPB (64 * 64)                           // 4096 B per tap (64 co x 64B)
#define WSZ (9 * WTAPB)                           // 36864
#define LDSZ (XSZ + WSZ)                          // 79104 -> 2 blocks/CU

__device__ __forceinline__ void gld_lds16(const void* g, void* l) {
  __builtin_amdgcn_global_load_lds(
      (const __attribute__((address_space(1))) unsigned int*)g,
      (__attribute__((address_space(3))) unsigned int*)l, 16, 0, 0);
}

// ---------------- K1: style ----------------
__global__ void style_kernel(const float* __restrict__ latent,
                             const float* __restrict__ affine_w,
                             const float* __restrict__ affine_b,
                             float* __restrict__ style) {
  const int idx = blockIdx.x * 256 + threadIdx.x;   // 8192
  const int b = idx >> 9, ci = idx & 511;
  const float* lp = latent + b * LL;
  const float* wp = affine_w + ci * LL;
  float acc = 0.f;
  for (int l = 0; l < LL; ++l) acc += lp[l] * wp[l];
  style[idx] = acc * 0.044194173824159216f + affine_b[ci];  // sqrt(1/512)
}

// ---------------- K2: weight sumsq + bf16 tap-major transform ----------------
__global__ void wprep_kernel(const float* __restrict__ conv_w,
                             float* __restrict__ wsq,
                             __hip_bfloat16* __restrict__ wt) {
  const int idx = blockIdx.x * 256 + threadIdx.x;   // 262144 = co*512+ci
  const int co = idx >> 9, ci = idx & 511;
  const float* wp = conv_w + idx * 9;
  float ss = 0.f;
#pragma unroll
  for (int t = 0; t < 9; ++t) {
    float v = wp[t];
    ss += v * v;
    wt[(t * COUT + co) * CIN + ci] = __float2bfloat16(v);
  }
  wsq[idx] = ss;
}

// ---------------- K3: demodulation scale ----------------
__global__ void dem_kernel(const float* __restrict__ wsq,
                           const float* __restrict__ style,
                           float* __restrict__ dem) {
  const int idx = blockIdx.x * 256 + threadIdx.x;   // 8192 = b*512+co
  const int b = idx >> 9, co = idx & 511;
  const float* sp = style + b * CIN;
  const float* wp = wsq + co * CIN;
  float acc = 0.f;
  for (int ci = 0; ci < CIN; ++ci) {
    float s = sp[ci];
    acc += wp[ci] * s * s;
  }
  dem[idx] = 1.0f / sqrtf(acc + 1e-8f);
}

// ---------------- K4: modulate + transpose to channel-last bf16 ----------------
__global__ void xsprep_kernel(const float* __restrict__ content,
                              const float* __restrict__ style,
                              __hip_bfloat16* __restrict__ xs) {
  __shared__ float tile[64][65];
  const int b = blockIdx.x >> 6;
  const int y = blockIdx.x & 63;
  const int tid = threadIdx.x;
  for (int cb = 0; cb < 8; ++cb) {
    const int ci0 = cb * 64;
    {
      const int x = tid & 63;
      const int c0 = tid >> 6;
#pragma unroll
      for (int p = 0; p < 16; ++p) {
        const int ci = p * 4 + c0;
        tile[ci][x] = content[((b * CIN + ci0 + ci) * HH + y) * WW + x];
      }
    }
    __syncthreads();
    {
      const int ci = tid & 63;
      const int x0 = tid >> 6;
      const float st = style[b * CIN + ci0 + ci];
#pragma unroll
      for (int p = 0; p < 16; ++p) {
        const int x = p * 4 + x0;
        xs[((b * HH + y) * WW + x) * CIN + ci0 + ci] =
            __float2bfloat16(tile[ci][x] * st);
      }
    }
    __syncthreads();
  }
}

// ---------------- K5: main MFMA conv ----------------
// grid: 1024 blocks (16 b x 8 yo x 8 cot, XCD-swizzled), 256 threads (4 waves).
// Block tile: 64 co x 8 rows. Wave wv owns rows y0+2wv, y0+2wv+1; 4x8 frags.
__global__ __launch_bounds__(256, 2) void conv_kernel(
    const __hip_bfloat16* __restrict__ xs,   // [B][H][W][CIN]
    const __hip_bfloat16* __restrict__ wt,   // [9][COUT][CIN]
    const float* __restrict__ dem,           // [B][COUT]
    const float* __restrict__ noise,         // [B][1][H][W]
    const float* __restrict__ biasp,         // [COUT]
    const float* __restrict__ nwp,           // scalar
    float* __restrict__ out) {
  __shared__ __attribute__((aligned(16))) char lds[LDSZ];

  const int tid = threadIdx.x;
  const int lane = tid & 63;
  const int wv = tid >> 6;

  // XCD swizzle: dispatch d -> XCD d%8; give each XCD a contiguous logical
  // chunk so the 8 cot-blocks sharing an X tile stay on one XCD's L2.
  const int d = blockIdx.x;                 // 0..1023
  const int L = (d & 7) * 128 + (d >> 3);   // bijective, 1024 % 8 == 0
  const int cot = L & 7;
  const int yo = (L >> 3) & 7;
  const int b = L >> 6;
  const int co0 = cot << 6;
  const int y0 = yo << 3;

  // zero X region once (halo rows/cols stay zero; interior overwritten per cib)
  for (int off = tid * 16; off < XSZ; off += 256 * 16)
    *(i32x4*)(lds + off) = (i32x4){0, 0, 0, 0};

  const int l15 = lane & 15;
  const int kg = lane >> 4;

  // per-lane LDS fragment-read offsets (XOR swizzle on 16B ci-chunk slot)
  int aoff[4];
#pragma unroll
  for (int mf = 0; mf < 4; ++mf) {
    const int co_l = l15 + mf * 16;
    const int fs = (co_l & 3) ^ ((co_l >> 2) & 3);
    aoff[mf] = co_l * 64 + ((kg ^ fs) << 4);
  }
  int boff[4][3];
#pragma unroll
  for (int q = 0; q < 4; ++q)
#pragma unroll
    for (int dx = 0; dx < 3; ++dx) {
      const int s = q * 16 + l15 + dx;
      const int fs = (s & 3) ^ ((s >> 2) & 3);
      boff[q][dx] = s * 64 + ((kg ^ fs) << 4);
    }

  // staging geometry: interior row slots rlo..rhi (slot = global_y - (y0-1))
  const int rlo = (yo == 0) ? 1 : 0;
  const int rhi = (yo == 7) ? 8 : 9;
  const int nxc = (rhi - rlo + 1) * 4;   // X chunks (1KB each)
  const int ntot = nxc + 36;             // + W chunks: 9 taps x 4

  const int xsub = lane >> 2;   // 0..15 within chunk
  const int slotl = lane & 3;   // 16B slot within 64B pixel/co block

  f32x4 acc[4][8];
#pragma unroll
  for (int mf = 0; mf < 4; ++mf)
#pragma unroll
    for (int nf = 0; nf < 8; ++nf) acc[mf][nf] = (f32x4){0.f, 0.f, 0.f, 0.f};

  __syncthreads();  // zero-init visible before first stage

  for (int cib = 0; cib < 16; ++cib) {
    const int ci0 = cib * 32;
    // ---- stage X interior rows + all 9 W taps ----
    for (int c = wv; c < ntot; c += 4) {
      if (c < nxc) {
        const int r = rlo + (c >> 2);
        const int q = c & 3;
        const int s = 1 + q * 16 + xsub;
        const int x = s - 1;
        const int y = y0 + r - 1;
        const int dcig = slotl ^ ((s & 3) ^ ((s >> 2) & 3));  // pre-swizzled source
        const __hip_bfloat16* g =
            xs + (((b << 6) + y) << 6 | x) * CIN + ci0 + dcig * 8;
        gld_lds16(g, lds + r * XROWB + 64 + q * 1024);
      } else {
        const int cw = c - nxc;
        const int tap = cw >> 2;
        const int q = cw & 3;
        const int co = q * 16 + xsub;
        const int dcig = slotl ^ ((co & 3) ^ ((co >> 2) & 3));
        const __hip_bfloat16* g =
            wt + ((tap << 9) + co0 + co) * CIN + ci0 + dcig * 8;
        gld_lds16(g, lds + XSZ + tap * WTAPB + q * 1024);
      }
    }
    __syncthreads();  // staged data visible

    // ---- compute: loop dx; share input-row B frags across (r,dy) ----
    const int rowbase = (2 * wv) * XROWB;
#pragma unroll
    for (int dx = 0; dx < 3; ++dx) {
      bf16x8 a[3][4];
#pragma unroll
      for (int dy = 0; dy < 3; ++dy)
#pragma unroll
        for (int mf = 0; mf < 4; ++mf)
          a[dy][mf] =
              *(const bf16x8*)(lds + XSZ + (dy * 3 + dx) * WTAPB + aoff[mf]);
#pragma unroll
      for (int ir = 0; ir < 4; ++ir) {
        const char* rp = lds + rowbase + ir * XROWB;
        bf16x8 bq[4];
#pragma unroll
        for (int q = 0; q < 4; ++q)
          bq[q] = *(const bf16x8*)(rp + boff[q][dx]);
#pragma unroll
        for (int dy = 0; dy < 3; ++dy) {
          const int r = ir - dy;
          if (r == 0 || r == 1) {
#pragma unroll
            for (int q = 0; q < 4; ++q)
#pragma unroll
              for (int mf = 0; mf < 4; ++mf)
                acc[mf][r * 4 + q] = __builtin_amdgcn_mfma_f32_16x16x32_bf16(
                    a[dy][mf], bq[q], acc[mf][r * 4 + q], 0, 0, 0);
          }
        }
      }
    }
    __syncthreads();  // compute done before next-step overwrite
  }

  // ---- epilogue: demod scale, noise, bias, lrelu*sqrt(2) ----
  const float nwv = nwp[0];
#pragma unroll
  for (int r = 0; r < 2; ++r) {
    const int y = y0 + 2 * wv + r;
    float nz[4];
#pragma unroll
    for (int q = 0; q < 4; ++q)
      nz[q] = nwv * noise[(b << 12) + (y << 6) + q * 16 + l15];

#pragma unroll
    for (int mf = 0; mf < 4; ++mf) {
      const int cobase = co0 + mf * 16 + kg * 4;
      const f32x4 dm = *(const f32x4*)(dem + (b << 9) + cobase);
      const f32x4 bs = *(const f32x4*)(biasp + cobase);
#pragma unroll
      for (int r2 = 0; r2 < 4; ++r2) {
        const int co = cobase + r2;
        float* op = out + ((((b << 9) + co) << 12) | (y << 6) | l15);
        const float dmv = dm[r2];
        const float bsv = bs[r2];
#pragma unroll
        for (int q = 0; q < 4; ++q) {
          float v = acc[mf][r * 4 + q][r2] * dmv + nz[q] + bsv;
          v = (v > 0.f ? v : 0.2f * v) * 1.41421356237309515f;
          op[q * 16] = v;
        }
      }
    }
  }
}

extern "C" void kernel_launch(void* const* d_in, const int* in_sizes, int n_in,
                              void* d_out, int out_size, void* d_ws, size_t ws_size,
                              hipStream_t stream) {
  const float* content  = (const float*)d_in[0];
  const float* latent   = (const float*)d_in[1];
  const float* noise    = (const float*)d_in[2];
  const float* affine_w = (const float*)d_in[3];
  const float* affine_b = (const float*)d_in[4];
  const float* conv_w   = (const float*)d_in[5];
  const float* bias     = (const float*)d_in[6];
  const float* nw       = (const float*)d_in[7];
  float* out = (float*)d_out;
  char* ws = (char*)d_ws;

  if (ws_size < (size_t)WS_NEEDED) return;

  __hip_bfloat16* xs = (__hip_bfloat16*)(ws + XS_OFF);
  __hip_bfloat16* wt = (__hip_bfloat16*)(ws + WT_OFF);
  float* style = (float*)(ws + STYLE_OFF);
  float* wsq   = (float*)(ws + WSQ_OFF);
  float* dem   = (float*)(ws + DEM_OFF);

  style_kernel<<<dim3(32), dim3(256), 0, stream>>>(latent, affine_w, affine_b, style);
  wprep_kernel<<<dim3(1024), dim3(256), 0, stream>>>(conv_w, wsq, wt);
  dem_kernel<<<dim3(32), dim3(256), 0, stream>>>(wsq, style, dem);
  xsprep_kernel<<<dim3(1024), dim3(256), 0, stream>>>(content, style, xs);
  conv_kernel<<<dim3(1024), dim3(256), 0, stream>>>(xs, wt, dem, noise, bias, nw, out);
}